// Round 7
// baseline (329.010 us; speedup 1.0000x reference)
//
#include <hip/hip_runtime.h>

#define HH 1024
#define INW 512
#define BB 32
#define Z_MIN_C 0.001f
#define Z_RANGE_C 0.099f
#define E_H_C 0.5f

typedef float v4f __attribute__((ext_vector_type(4)));

__device__ __forceinline__ float sigmoidf_(float v) {
    return 1.0f / (1.0f + __expf(-v));
}

// ---------------- Kernel P: precompute sigmoid-derived params ----------------
// One block per row j; thread t owns k = 4t..4t+3. Writes 4 streams (16 MB):
//   zxA  = z_x                  = ZMIN + ZR*sig(c_x)
//   ozuA = 1 - z_u
//   ucA  = Ucap                 = 0.9*sig(c_U)
//   AA   = Ucap * z_u
// Same j->XCD mapping as the consumer (bid % 8 == j % 8), so these land in
// the L2 that kernel B's 32 blocks of row j will read from.
__global__ __launch_bounds__(256) void param_kernel(
    const float* __restrict__ c_x,
    const float* __restrict__ c_u,
    const float* __restrict__ c_U,
    float* __restrict__ zxA, float* __restrict__ ozuA,
    float* __restrict__ ucA, float* __restrict__ AA)
{
    const int idx = blockIdx.x * HH + threadIdx.x * 4;
    v4f cx4 = __builtin_nontemporal_load((const v4f*)(c_x + idx));
    v4f cu4 = __builtin_nontemporal_load((const v4f*)(c_u + idx));
    v4f cC4 = __builtin_nontemporal_load((const v4f*)(c_U + idx));
    v4f zx4, ozu4, uc4, A4;
    #pragma unroll
    for (int c = 0; c < 4; ++c) {
        float zx = Z_MIN_C + Z_RANGE_C * sigmoidf_(cx4[c]);
        float zu = Z_MIN_C + Z_RANGE_C * sigmoidf_(cu4[c]);
        float uc = 0.9f * sigmoidf_(cC4[c]);
        zx4[c] = zx;
        ozu4[c] = 1.0f - zu;
        uc4[c] = uc;
        A4[c] = uc * zu;
    }
    *(v4f*)(zxA + idx) = zx4;
    *(v4f*)(ozuA + idx) = ozu4;
    *(v4f*)(ucA + idx) = uc4;
    *(v4f*)(AA + idx) = A4;
}

// ---------------- Kernel A: pre0[b,j] = (p @ x)[j,b] + bias[j] ----------------
__global__ __launch_bounds__(256) void px_kernel(
    const float* __restrict__ x,    // (IN, B)
    const float* __restrict__ p,    // (H, IN)
    const float* __restrict__ bias, // (H, 1)
    float* __restrict__ pre0)       // (B, H)
{
    const int wv = threadIdx.x >> 6;
    const int lane = threadIdx.x & 63;
    const int j = blockIdx.x * 4 + wv;
    const int b = lane & 31;
    const int half = lane >> 5;

    const float* pr = p + j * INW + half * 256;
    const float* xc = x + (half * 256) * BB + b;
    float acc = 0.0f;
    #pragma unroll 8
    for (int i = 0; i < 256; ++i)
        acc = fmaf(pr[i], xc[i * BB], acc);
    acc += __shfl_xor(acc, 32);
    if (lane < 32)
        pre0[lane * HH + j] = acc + bias[j];
}

// ---------------- Kernel B: one block per (b,j) row, zero transcendentals ----
// 32768 tiny blocks: linear X/U sweep, 128-deep block queue per CU (R6's good
// memory behavior) with the R6 VALU overhead removed (80% -> ~30% predicted):
// per element ~13 FMA-class ops, params read from the precomputed L2-hot
// streams instead of 3 sigmoid evals.
__global__ __launch_bounds__(256, 4) void stp_fused(
    const float* __restrict__ h,    // (B, H)
    const float* __restrict__ X,    // (B, H, H)
    const float* __restrict__ U,    // (B, H, H)
    const float* __restrict__ c_h,  // (H, 1)
    const float* __restrict__ w,    // (H, H)
    const float* __restrict__ zxA,  // precomputed z_x
    const float* __restrict__ ozuA, // precomputed 1 - z_u
    const float* __restrict__ ucA,  // precomputed Ucap
    const float* __restrict__ AA,   // precomputed Ucap*z_u
    const float* __restrict__ pre0, // (B, H)
    float* __restrict__ out)        // (B, H)
{
    const int bid = blockIdx.x;
    const int j = bid & (HH - 1);
    const int b = bid >> 10;
    const int t = threadIdx.x;
    const int lane = t & 63;
    const int wave = t >> 6;
    const int k0 = t * 4;

    __shared__ float rec_part[4];

    // ---- post long-latency streaming loads first ----
    const int rowbase = bid * HH;
    v4f Xv = __builtin_nontemporal_load((const v4f*)(X + rowbase + k0));
    v4f Uv = __builtin_nontemporal_load((const v4f*)(U + rowbase + k0));
    v4f hk = *(const v4f*)(h + b * HH + k0);
    const float hjv = h[bid];
    const float pv = pre0[bid];
    const float chj = c_h[j];

    // ---- derived-param loads (L2-hot) under the X/U flight ----
    const int pbase = j * HH + k0;
    v4f zx4 = *(const v4f*)(zxA + pbase);
    v4f ozu4 = *(const v4f*)(ozuA + pbase);
    v4f uc4 = *(const v4f*)(ucA + pbase);
    v4f A4 = *(const v4f*)(AA + pbase);
    v4f wv4 = *(const v4f*)(w + pbase);

    float ss = 0.0f;
    #pragma unroll
    for (int c = 0; c < 4; ++c) {
        // U_new = (A + uh) + (ozu - uh)*U, clamped to [Ucap, 1]
        const float uh = uc4[c] * hjv;
        float Un = fmaf(ozu4[c] - uh, Uv[c], A4[c] + uh);
        Un = fminf(fmaxf(Un, uc4[c]), 1.0f);
        // X_new = zx + (1-zx)*X - U*(X*hj)
        float Xn = fmaf(1.0f - zx4[c], Xv[c], zx4[c]);
        Xn = fmaf(-Uv[c], Xv[c] * hjv, Xn);
        // rec contribution: w*U_new*X_new*h[b,k]
        ss = fmaf(wv4[c] * hk[c], Un * Xn, ss);
    }

    // ---- single cross-lane reduction ----
    #pragma unroll
    for (int off = 32; off > 0; off >>= 1)
        ss += __shfl_xor(ss, off);
    if (lane == 0) rec_part[wave] = ss;
    __syncthreads();

    // ---- finalize (sole owner of (b,j)) ----
    if (t == 0) {
        const float rec = rec_part[0] + rec_part[1] + rec_part[2] + rec_part[3];
        const float pre = pv + rec;
        const float zh = E_H_C * sigmoidf_(chj);
        out[bid] = (1.0f - zh) * hjv + zh * sigmoidf_(pre);
    }
}

extern "C" void kernel_launch(void* const* d_in, const int* in_sizes, int n_in,
                              void* d_out, int out_size, void* d_ws, size_t ws_size,
                              hipStream_t stream) {
    const float* x   = (const float*)d_in[0];
    const float* h   = (const float*)d_in[1];
    const float* X   = (const float*)d_in[2];
    const float* U   = (const float*)d_in[3];
    const float* c_x = (const float*)d_in[4];
    const float* c_u = (const float*)d_in[5];
    const float* c_U = (const float*)d_in[6];
    const float* c_h = (const float*)d_in[7];
    const float* w   = (const float*)d_in[8];
    const float* p   = (const float*)d_in[9];
    const float* b   = (const float*)d_in[10];
    float* out = (float*)d_out;

    float* ws = (float*)d_ws;            // ws_size ~512 MB (poison fill = 512 MB)
    float* pre0 = ws;                    // 32*1024 floats  = 128 KB
    float* zxA  = ws + 32768;            // 1M floats = 4 MB
    float* ozuA = zxA + HH * HH;
    float* ucA  = ozuA + HH * HH;
    float* AA   = ucA + HH * HH;         // total 128 KB + 16 MB

    param_kernel<<<HH, 256, 0, stream>>>(c_x, c_u, c_U, zxA, ozuA, ucA, AA);
    px_kernel<<<HH / 4, 256, 0, stream>>>(x, p, b, pre0);
    stp_fused<<<BB * HH, 256, 0, stream>>>(h, X, U, c_h, w, zxA, ozuA, ucA, AA,
                                           pre0, out);
}

// Round 8
// 312.384 us; speedup vs baseline: 1.0532x; 1.0532x over previous
//
#include <hip/hip_runtime.h>

#define HH 1024
#define INW 512
#define BB 32
#define BG 8             // batches per block: params amortized x8
#define Z_MIN_C 0.001f
#define Z_RANGE_C 0.099f
#define E_H_C 0.5f

typedef float v4f __attribute__((ext_vector_type(4)));

__device__ __forceinline__ float sigmoidf_(float v) {
    return 1.0f / (1.0f + __expf(-v));
}

// ---------------- Kernel P: precompute sigmoid-derived params ----------------
// zxA = z_x; ozuA = 1-z_u; ucA = Ucap; AA = Ucap*z_u. bid==j -> same XCD as
// the consumers of row j (all 4096 consumer blocks of row j are j mod 1024).
__global__ __launch_bounds__(256) void param_kernel(
    const float* __restrict__ c_x,
    const float* __restrict__ c_u,
    const float* __restrict__ c_U,
    float* __restrict__ zxA, float* __restrict__ ozuA,
    float* __restrict__ ucA, float* __restrict__ AA)
{
    const int idx = blockIdx.x * HH + threadIdx.x * 4;
    v4f cx4 = __builtin_nontemporal_load((const v4f*)(c_x + idx));
    v4f cu4 = __builtin_nontemporal_load((const v4f*)(c_u + idx));
    v4f cC4 = __builtin_nontemporal_load((const v4f*)(c_U + idx));
    v4f zx4, ozu4, uc4, A4;
    #pragma unroll
    for (int c = 0; c < 4; ++c) {
        float zx = Z_MIN_C + Z_RANGE_C * sigmoidf_(cx4[c]);
        float zu = Z_MIN_C + Z_RANGE_C * sigmoidf_(cu4[c]);
        float uc = 0.9f * sigmoidf_(cC4[c]);
        zx4[c] = zx;
        ozu4[c] = 1.0f - zu;
        uc4[c] = uc;
        A4[c] = uc * zu;
    }
    *(v4f*)(zxA + idx) = zx4;
    *(v4f*)(ozuA + idx) = ozu4;
    *(v4f*)(ucA + idx) = uc4;
    *(v4f*)(AA + idx) = A4;
}

// ---------------- Kernel A: pre0[b,j] = (p @ x)[j,b] + bias[j] ----------------
__global__ __launch_bounds__(256) void px_kernel(
    const float* __restrict__ x,    // (IN, B)
    const float* __restrict__ p,    // (H, IN)
    const float* __restrict__ bias, // (H, 1)
    float* __restrict__ pre0)       // (B, H)
{
    const int wv = threadIdx.x >> 6;
    const int lane = threadIdx.x & 63;
    const int j = blockIdx.x * 4 + wv;
    const int b = lane & 31;
    const int half = lane >> 5;

    const float* pr = p + j * INW + half * 256;
    const float* xc = x + (half * 256) * BB + b;
    float acc = 0.0f;
    #pragma unroll 8
    for (int i = 0; i < 256; ++i)
        acc = fmaf(pr[i], xc[i * BB], acc);
    acc += __shfl_xor(acc, 32);
    if (lane < 32)
        pre0[lane * HH + j] = acc + bias[j];
}

// ---------------- Kernel B: (j, batch-group of 8), rotating prefetch ----------
// Grid 4096: j = bid & 1023, g = bid >> 10. Params loaded ONCE per block
// (amortized over 8 batches: per-launch param L1 traffic 640 MB -> 80 MB vs
// R7) and held in registers; hj scalars are block-uniform -> SGPRs. Depth-4
// rotating prefetch of {X,U,hk} keeps 12 v4f (192 B/lane) posted while the
// previous iteration's ~40 VALU ops consume. Reductions deferred per-batch.
__global__ __launch_bounds__(256, 4) void stp_fused(
    const float* __restrict__ h,    // (B, H)
    const float* __restrict__ X,    // (B, H, H)
    const float* __restrict__ U,    // (B, H, H)
    const float* __restrict__ c_h,  // (H, 1)
    const float* __restrict__ w,    // (H, H)
    const float* __restrict__ zxA,  // z_x
    const float* __restrict__ ozuA, // 1 - z_u
    const float* __restrict__ ucA,  // Ucap
    const float* __restrict__ AA,   // Ucap*z_u
    const float* __restrict__ pre0, // (B, H)
    float* __restrict__ out)        // (B, H)
{
    const int j = blockIdx.x & (HH - 1);
    const int g = blockIdx.x >> 10;          // 0..3
    const int b0 = g * BG;
    const int t = threadIdx.x;
    const int lane = t & 63;
    const int wave = t >> 6;
    const int k0 = t * 4;

    __shared__ float rec_part[BG][4];

    // ---- post first prefetch window (4 x {X,U,hk}) before anything else ----
    v4f Xs[4], Us[4], hs[4];
    #pragma unroll
    for (int i = 0; i < 4; ++i) {
        const int b = b0 + i;
        const int rb = (b * HH + j) * HH + k0;
        Xs[i] = __builtin_nontemporal_load((const v4f*)(X + rb));
        Us[i] = __builtin_nontemporal_load((const v4f*)(U + rb));
        hs[i] = *(const v4f*)(h + b * HH + k0);
    }

    // ---- per-row data under the prefetch flight ----
    const int pbase = j * HH + k0;
    v4f zx4 = *(const v4f*)(zxA + pbase);
    v4f ozu4 = *(const v4f*)(ozuA + pbase);
    v4f uc4 = *(const v4f*)(ucA + pbase);
    v4f A4 = *(const v4f*)(AA + pbase);
    v4f wv4 = *(const v4f*)(w + pbase);

    float hj[BG];                            // block-uniform -> scalar loads
    #pragma unroll
    for (int i = 0; i < BG; ++i) hj[i] = h[(b0 + i) * HH + j];

    // ---- streaming loop: consume slot i&3, refill for i+4 ----
    float s[BG];
    #pragma unroll
    for (int i = 0; i < BG; ++i) {
        const int sl = i & 3;
        v4f Xv = Xs[sl];
        v4f Uv = Us[sl];
        v4f hk = hs[sl];
        if (i + 4 < BG) {
            const int b = b0 + i + 4;
            const int rb = (b * HH + j) * HH + k0;
            Xs[sl] = __builtin_nontemporal_load((const v4f*)(X + rb));
            Us[sl] = __builtin_nontemporal_load((const v4f*)(U + rb));
            hs[sl] = *(const v4f*)(h + b * HH + k0);
        }
        const float hjv = hj[i];
        float ss = 0.0f;
        #pragma unroll
        for (int c = 0; c < 4; ++c) {
            // U_new = (A + uh) + ((1-z_u) - uh)*U, clamped to [Ucap, 1]
            const float uh = uc4[c] * hjv;
            float Un = fmaf(ozu4[c] - uh, Uv[c], A4[c] + uh);
            Un = fminf(fmaxf(Un, uc4[c]), 1.0f);
            // X_new = zx + (1-zx)*X - U*(X*hj)
            float Xn = fmaf(1.0f - zx4[c], Xv[c], zx4[c]);
            Xn = fmaf(-Uv[c], Xv[c] * hjv, Xn);
            ss = fmaf(wv4[c] * hk[c], Un * Xn, ss);
        }
        s[i] = ss;
    }

    // ---- deferred reductions: 8 independent shuffle chains ----
    #pragma unroll
    for (int i = 0; i < BG; ++i) {
        float v = s[i];
        #pragma unroll
        for (int off = 32; off > 0; off >>= 1)
            v += __shfl_xor(v, off);
        if (lane == 0) rec_part[i][wave] = v;
    }
    __syncthreads();

    // ---- finalize: thread t = local batch (sole owner of (b,j)) ----
    if (t < BG) {
        const int b = b0 + t;
        const float rec = rec_part[t][0] + rec_part[t][1] + rec_part[t][2] + rec_part[t][3];
        const float pre = pre0[b * HH + j] + rec;
        const float zh = E_H_C * sigmoidf_(c_h[j]);
        const float hv = h[b * HH + j];
        out[b * HH + j] = (1.0f - zh) * hv + zh * sigmoidf_(pre);
    }
}

extern "C" void kernel_launch(void* const* d_in, const int* in_sizes, int n_in,
                              void* d_out, int out_size, void* d_ws, size_t ws_size,
                              hipStream_t stream) {
    const float* x   = (const float*)d_in[0];
    const float* h   = (const float*)d_in[1];
    const float* X   = (const float*)d_in[2];
    const float* U   = (const float*)d_in[3];
    const float* c_x = (const float*)d_in[4];
    const float* c_u = (const float*)d_in[5];
    const float* c_U = (const float*)d_in[6];
    const float* c_h = (const float*)d_in[7];
    const float* w   = (const float*)d_in[8];
    const float* p   = (const float*)d_in[9];
    const float* b   = (const float*)d_in[10];
    float* out = (float*)d_out;

    float* ws = (float*)d_ws;            // ws_size ~512 MB
    float* pre0 = ws;                    // 128 KB
    float* zxA  = ws + 32768;            // 4 MB each
    float* ozuA = zxA + HH * HH;
    float* ucA  = ozuA + HH * HH;
    float* AA   = ucA + HH * HH;

    param_kernel<<<HH, 256, 0, stream>>>(c_x, c_u, c_U, zxA, ozuA, ucA, AA);
    px_kernel<<<HH / 4, 256, 0, stream>>>(x, p, b, pre0);
    stp_fused<<<HH * 4, 256, 0, stream>>>(h, X, U, c_h, w, zxA, ozuA, ucA, AA,
                                          pre0, out);
}